// Round 1
// baseline (971.758 us; speedup 1.0000x reference)
//
#include <hip/hip_runtime.h>

#define Bn 16
#define Nn 1024
#define DIN 32
#define DZ 64
#define Fc 3
#define Pp 19
#define PPAD 20
#define Ee 171
#define ITERS 50
#define INV_SCALE (19.0f/1024.0f)
#define CHUNK 64

// workspace offsets (in floats); total = 1,100,576 floats = 4.4 MB
#define OFF_WPROJ 0         // [B][F][N][PPAD]  983040
#define OFF_FFULL 983040    // [B][N][F]        49152
#define OFF_ZP    1032192   // [B][64]          1024
#define OFF_FLAT  1033216   // [B][F][19]       912
#define OFF_UBUF  1034128   // [B][57]          912
#define OFF_BVALS 1035040   // [B][N][F]        49152   -- zero region start
#define OFF_ZACC  1084192   // [B][64]          1024
#define OFF_KHAT  1085216   // [B][F][16][19]   14592
#define OFF_SRC   1099808   // [B][F][16]       768
#define ZERO_FLOATS 65536   // BVALS+ZACC+KHAT+SRC contiguous

// ---------------- scatter boundary_vals (deterministic last-wins) ----------------
__global__ void k_scatter(const int* __restrict__ nodes, const float* __restrict__ bvals,
                          float* __restrict__ bfull) {
  int b = threadIdx.x;
  if (b >= Bn) return;
  for (int j = 0; j < 64; j++) {
    int node = nodes[b*64 + j];
    #pragma unroll
    for (int f = 0; f < Fc; f++)
      bfull[(b*Nn + node)*Fc + f] = bvals[(b*64 + j)*Fc + f];
  }
}

// ---------------- encoder + POU softmax + f_full + zacc partials ----------------
__global__ __launch_bounds__(128) void k_encode(
    const float* __restrict__ x, const float* __restrict__ Wenc, const float* __restrict__ benc,
    const float* __restrict__ Wsrc, const float* __restrict__ bsrc, const float* __restrict__ Wpou,
    const float* __restrict__ bfull, float* __restrict__ wproj, float* __restrict__ ffull,
    float* __restrict__ zacc) {
  __shared__ float sWenc[DIN*DZ];
  __shared__ float sWpou[DZ*57];
  __shared__ float sWsrc[DZ*Fc];
  int tid = threadIdx.x;
  for (int t = tid; t < DIN*DZ; t += 128) sWenc[t] = Wenc[t];
  for (int t = tid; t < DZ*57; t += 128) sWpou[t] = Wpou[t];
  for (int t = tid; t < DZ*Fc; t += 128) sWsrc[t] = Wsrc[t];
  __syncthreads();
  int g = blockIdx.x*128 + tid;         // b*N + i
  int b = g >> 10, i = g & 1023;
  float xr[DIN];
  const float* xp = x + (size_t)g*DIN;
  #pragma unroll
  for (int k = 0; k < DIN; k += 4) {
    float4 t4 = *(const float4*)(xp + k);
    xr[k] = t4.x; xr[k+1] = t4.y; xr[k+2] = t4.z; xr[k+3] = t4.w;
  }
  float l[57];
  #pragma unroll
  for (int o = 0; o < 57; o++) l[o] = 0.f;
  float ff[3] = {bsrc[0], bsrc[1], bsrc[2]};
  int lane = tid & 63;
  for (int d = 0; d < DZ; d++) {
    float zd = benc[d];
    #pragma unroll
    for (int k = 0; k < DIN; k++) zd = fmaf(xr[k], sWenc[k*DZ + d], zd);
    zd = tanhf(zd);
    #pragma unroll
    for (int o = 0; o < 57; o++) l[o] = fmaf(zd, sWpou[d*57 + o], l[o]);
    #pragma unroll
    for (int f = 0; f < Fc; f++) ff[f] = fmaf(zd, sWsrc[d*Fc + f], ff[f]);
    float zs = zd;
    #pragma unroll
    for (int off = 32; off > 0; off >>= 1) zs += __shfl_xor(zs, off, 64);
    if (lane == 0) atomicAdd(&zacc[b*DZ + d], zs);
  }
  #pragma unroll
  for (int f = 0; f < Fc; f++) ffull[(size_t)g*Fc + f] = ff[f];
  #pragma unroll
  for (int f = 0; f < Fc; f++) {
    float bv = bfull[(size_t)g*Fc + f];
    l[16*3+f] += bv; l[17*3+f] += bv; l[18*3+f] += bv;
  }
  #pragma unroll
  for (int f = 0; f < Fc; f++) {
    float m = l[f];
    #pragma unroll
    for (int p = 1; p < Pp; p++) m = fmaxf(m, l[p*3+f]);
    float ex[Pp]; float s = 0.f;
    #pragma unroll
    for (int p = 0; p < Pp; p++) { ex[p] = __expf(l[p*3+f] - m); s += ex[p]; }
    float inv = 1.f / s;
    float* wp = wproj + ((size_t)(b*Fc + f)*Nn + i)*PPAD;
    #pragma unroll
    for (int p = 0; p < Pp; p++) wp[p] = ex[p]*inv;
  }
}

// ---------------- zp = mean(z) @ Wz ----------------
__global__ void k_zp(const float* __restrict__ zacc, const float* __restrict__ Wz,
                     float* __restrict__ zp) {
  int b = blockIdx.x, d = threadIdx.x;    // 64 threads
  float s = 0.f;
  for (int k = 0; k < DZ; k++) s = fmaf(zacc[b*DZ + k] * (1.f/1024.f), Wz[k*DZ + d], s);
  zp[b*DZ + d] = s;
}

// ---------------- f_latent[b,f,q] = (1/scale) sum_i W[q,i] f_full[i,f] ----------------
__global__ __launch_bounds__(256) void k_flat(const float* __restrict__ wproj,
                                              const float* __restrict__ ffull,
                                              float* __restrict__ flat) {
  int bf = blockIdx.x;                 // b*3+f
  int b = bf / 3, f = bf % 3;
  float acc[Pp];
  #pragma unroll
  for (int q = 0; q < Pp; q++) acc[q] = 0.f;
  for (int i = threadIdx.x; i < Nn; i += 256) {
    float fv = ffull[((size_t)b*Nn + i)*Fc + f];
    const float* row = wproj + ((size_t)bf*Nn + i)*PPAD;
    #pragma unroll
    for (int q = 0; q < Pp; q++) acc[q] = fmaf(row[q], fv, acc[q]);
  }
  #pragma unroll
  for (int q = 0; q < Pp; q++) {
    float v = acc[q];
    #pragma unroll
    for (int off = 32; off > 0; off >>= 1) v += __shfl_xor(v, off, 64);
    acc[q] = v;
  }
  __shared__ float red[4][Pp];
  int wave = threadIdx.x >> 6, lane = threadIdx.x & 63;
  if (lane == 0) {
    #pragma unroll
    for (int q = 0; q < Pp; q++) red[wave][q] = acc[q];
  }
  __syncthreads();
  if (threadIdx.x < Pp) {
    float s = red[0][threadIdx.x] + red[1][threadIdx.x] + red[2][threadIdx.x] + red[3][threadIdx.x];
    flat[bf*Pp + threadIdx.x] = s * INV_SCALE;
  }
}

// ---------------- the heavy pass: stream K & M once ----------------
// K_hat[p<16][q] += (1/scale) * sum_j (sum_i W[p,i]K[i,j]) W[q,j]
// src[p<16]     += (1/scale) * sum_i W[p,i] sum_j M[i,j] v[j],  v = W^T f_latent
__global__ __launch_bounds__(256) void k_project(
    const float* __restrict__ Kl, const float* __restrict__ Ml,
    const float* __restrict__ wproj, const float* __restrict__ flat,
    float* __restrict__ khat, float* __restrict__ srca) {
  int chunk = blockIdx.x;              // 16 i-chunks of 64
  int bf = blockIdx.y;                 // 48
  int i0 = chunk * CHUNK;
  const float* Kb = Kl + (size_t)bf*Nn*Nn;
  const float* Mb = Ml + (size_t)bf*Nn*Nn;
  const float* Wp = wproj + (size_t)bf*Nn*PPAD;
  __shared__ float Ws[CHUNK*PPAD];
  int tid = threadIdx.x;
  for (int t = tid; t < CHUNK*PPAD; t += 256) Ws[t] = Wp[(size_t)i0*PPAD + t];
  float fl[Pp];
  #pragma unroll
  for (int q = 0; q < Pp; q++) fl[q] = flat[bf*Pp + q];
  __syncthreads();
  int j0 = tid * 4;
  float v[4];
  #pragma unroll
  for (int r = 0; r < 4; r++) {
    const float* row = Wp + (size_t)(j0 + r)*PPAD;
    float s = 0.f;
    #pragma unroll
    for (int q = 0; q < Pp; q++) s = fmaf(row[q], fl[q], s);
    v[r] = s;
  }
  float acc[Pp][4];
  float sa[16];
  #pragma unroll
  for (int p = 0; p < Pp; p++) { acc[p][0]=0.f; acc[p][1]=0.f; acc[p][2]=0.f; acc[p][3]=0.f; }
  #pragma unroll
  for (int p = 0; p < 16; p++) sa[p] = 0.f;
  const float* kp = Kb + (size_t)i0*Nn + j0;
  const float* mp = Mb + (size_t)i0*Nn + j0;
  for (int ii = 0; ii < CHUNK; ii++) {
    float4 k4 = *(const float4*)kp; kp += Nn;
    float4 m4 = *(const float4*)mp; mp += Nn;
    float tm = m4.x*v[0] + m4.y*v[1] + m4.z*v[2] + m4.w*v[3];
    const float* w = Ws + ii*PPAD;
    #pragma unroll
    for (int p = 0; p < Pp; p++) {
      float wv = w[p];
      acc[p][0] = fmaf(wv, k4.x, acc[p][0]);
      acc[p][1] = fmaf(wv, k4.y, acc[p][1]);
      acc[p][2] = fmaf(wv, k4.z, acc[p][2]);
      acc[p][3] = fmaf(wv, k4.w, acc[p][3]);
      if (p < 16) sa[p] = fmaf(wv, tm, sa[p]);
    }
  }
  // stage 2: contract partial T against W^T over this thread's 4 columns
  float wrow[4][Pp];
  #pragma unroll
  for (int r = 0; r < 4; r++) {
    const float* row = Wp + (size_t)(j0 + r)*PPAD;
    #pragma unroll
    for (int q = 0; q < Pp; q++) wrow[r][q] = row[q];
  }
  int lane = tid & 63;
  #pragma unroll
  for (int p = 0; p < 16; p++) {
    float pr[Pp];
    #pragma unroll
    for (int q = 0; q < Pp; q++)
      pr[q] = acc[p][0]*wrow[0][q] + acc[p][1]*wrow[1][q] + acc[p][2]*wrow[2][q] + acc[p][3]*wrow[3][q];
    #pragma unroll
    for (int q = 0; q < Pp; q++) {
      float vq = pr[q];
      #pragma unroll
      for (int off = 32; off > 0; off >>= 1) vq += __shfl_xor(vq, off, 64);
      pr[q] = vq;
    }
    if (lane == 0) {
      for (int q = 0; q < Pp; q++)
        atomicAdd(&khat[(bf*16 + p)*Pp + q], pr[q] * INV_SCALE);
    }
  }
  #pragma unroll
  for (int p = 0; p < 16; p++) {
    float vq = sa[p];
    #pragma unroll
    for (int off = 32; off > 0; off >>= 1) vq += __shfl_xor(vq, off, 64);
    sa[p] = vq;
  }
  if (lane == 0) {
    for (int p = 0; p < 16; p++) atomicAdd(&srca[bf*16 + p], sa[p] * INV_SCALE);
  }
}

// ---------------- damped fixed-point solver: one block per batch ----------------
__global__ __launch_bounds__(512) void k_solve(
    const float* __restrict__ khat, const float* __restrict__ srca,
    const float* __restrict__ zp, const float* __restrict__ u_init,
    const float* __restrict__ Wf1, const float* __restrict__ bfv,
    const float* __restrict__ Wf2, float* __restrict__ ubuf) {
  int b = blockIdx.x;
  __shared__ float u_s[57];
  __shared__ float flux_s[Ee*Fc];
  __shared__ float sW1[6*DZ];
  __shared__ float sW2[DZ*Fc];
  __shared__ float sbz[DZ];
  __shared__ float sK[Fc*16*Pp];
  __shared__ float ssrc[Fc*16];
  int tid = threadIdx.x;
  for (int t = tid; t < 6*DZ; t += 512) sW1[t] = Wf1[t];
  for (int t = tid; t < DZ*Fc; t += 512) sW2[t] = Wf2[t];
  if (tid < DZ) sbz[tid] = bfv[tid] + zp[b*DZ + tid];
  for (int t = tid; t < Fc*16*Pp; t += 512) sK[t] = khat[b*Fc*16*Pp + t];
  if (tid < 48) ssrc[tid] = srca[b*48 + tid];
  if (tid < 57) u_s[tid] = u_init[b*57 + tid];
  __syncthreads();
  int e = tid >> 1, h = tid & 1;
  bool active = (e < Ee);
  int ei = 0, ej = 0;
  if (active) {
    int r = e, i = 0;
    while (r >= 18 - i) { r -= 18 - i; i++; }
    ei = i; ej = i + 1 + r;
  }
  int d0 = h * 32;
  for (int it = 0; it < ITERS; it++) {
    if (active) {
      float ue[6];
      #pragma unroll
      for (int f = 0; f < Fc; f++) { ue[f] = u_s[ei*3 + f]; ue[3+f] = u_s[ej*3 + f]; }
      float fl0 = 0.f, fl1 = 0.f, fl2 = 0.f;
      for (int dd = 0; dd < 32; dd++) {
        int d = d0 + dd;
        float pre = sbz[d];
        #pragma unroll
        for (int k = 0; k < 6; k++) pre = fmaf(ue[k], sW1[k*DZ + d], pre);
        float xc = fminf(fmaxf(pre, -20.f), 20.f);
        float t = __expf(2.f * xc);
        float th = (t - 1.f) / (t + 1.f);
        fl0 = fmaf(th, sW2[d*3 + 0], fl0);
        fl1 = fmaf(th, sW2[d*3 + 1], fl1);
        fl2 = fmaf(th, sW2[d*3 + 2], fl2);
      }
      fl0 += __shfl_xor(fl0, 1, 64);
      fl1 += __shfl_xor(fl1, 1, 64);
      fl2 += __shfl_xor(fl2, 1, 64);
      if (h == 0) { flux_s[e*3+0] = fl0; flux_s[e*3+1] = fl1; flux_s[e*3+2] = fl2; }
    }
    __syncthreads();
    if (tid < 57) {
      int p = tid / 3, f = tid % 3;
      float u_old = u_s[tid];
      float r_;
      if (p < 16) {
        float diff = 0.f;
        for (int q = 0; q < Pp; q++) diff = fmaf(sK[(f*16 + p)*Pp + q], u_s[q*3 + f], diff);
        float ft = 0.f;
        for (int o = 0; o < Pp; o++) {
          if (o == p) continue;
          int i_ = (o < p) ? o : p;
          int j_ = (o < p) ? p : o;
          int eidx = i_*Pp - (i_*(i_+1))/2 + (j_ - i_ - 1);
          float sgn = (o < p) ? 1.f : -1.f;   // delta0[e, ej]=+1, delta0[e, ei]=-1
          ft += sgn * flux_s[eidx*3 + f];
        }
        r_ = diff - ssrc[f*16 + p] - ft;
      } else {
        r_ = u_old - ((p == 16) ? 1.f : 0.f);
      }
      u_s[tid] = u_old - 0.1f * r_;
    }
    __syncthreads();
  }
  if (tid < 57) ubuf[b*57 + tid] = u_s[tid];
}

// ---------------- u_fine = einsum('bpif,bpf->bif') ----------------
__global__ __launch_bounds__(256) void k_out(const float* __restrict__ wproj,
                                             const float* __restrict__ ubuf,
                                             float* __restrict__ out) {
  __shared__ float u_s[57];
  int b = blockIdx.y;
  int i = blockIdx.x*256 + threadIdx.x;
  if (threadIdx.x < 57) u_s[threadIdx.x] = ubuf[b*57 + threadIdx.x];
  __syncthreads();
  #pragma unroll
  for (int f = 0; f < Fc; f++) {
    const float* row = wproj + ((size_t)(b*Fc + f)*Nn + i)*PPAD;
    float s = 0.f;
    #pragma unroll
    for (int p = 0; p < Pp; p++) s = fmaf(row[p], u_s[p*3 + f], s);
    out[((size_t)b*Nn + i)*Fc + f] = s;
  }
}

extern "C" void kernel_launch(void* const* d_in, const int* in_sizes, int n_in,
                              void* d_out, int out_size, void* d_ws, size_t ws_size,
                              hipStream_t stream) {
  const float* in_tokens = (const float*)d_in[0];
  const float* K_list    = (const float*)d_in[1];
  const float* M_list    = (const float*)d_in[2];
  const int*   dnodes    = (const int*)d_in[3];
  const float* bvals     = (const float*)d_in[4];
  const float* u_init    = (const float*)d_in[5];
  const float* W_enc     = (const float*)d_in[6];
  const float* b_enc     = (const float*)d_in[7];
  const float* W_src     = (const float*)d_in[8];
  const float* b_src     = (const float*)d_in[9];
  const float* W_pou     = (const float*)d_in[10];
  const float* Wf1       = (const float*)d_in[11];
  const float* Wz        = (const float*)d_in[12];
  const float* bfv       = (const float*)d_in[13];
  const float* Wf2       = (const float*)d_in[14];
  float* ws  = (float*)d_ws;
  float* out = (float*)d_out;

  float* WPROJ = ws + OFF_WPROJ;
  float* FFULL = ws + OFF_FFULL;
  float* ZP    = ws + OFF_ZP;
  float* FLAT  = ws + OFF_FLAT;
  float* UBUF  = ws + OFF_UBUF;
  float* BVALS = ws + OFF_BVALS;
  float* ZACC  = ws + OFF_ZACC;
  float* KHAT  = ws + OFF_KHAT;
  float* SRC   = ws + OFF_SRC;

  hipMemsetAsync(ws + OFF_BVALS, 0, (size_t)ZERO_FLOATS * sizeof(float), stream);
  k_scatter<<<1, 64, 0, stream>>>(dnodes, bvals, BVALS);
  k_encode<<<128, 128, 0, stream>>>(in_tokens, W_enc, b_enc, W_src, b_src, W_pou,
                                    BVALS, WPROJ, FFULL, ZACC);
  k_zp<<<Bn, 64, 0, stream>>>(ZACC, Wz, ZP);
  k_flat<<<Bn*Fc, 256, 0, stream>>>(WPROJ, FFULL, FLAT);
  k_project<<<dim3(Nn/CHUNK, Bn*Fc), 256, 0, stream>>>(K_list, M_list, WPROJ, FLAT, KHAT, SRC);
  k_solve<<<Bn, 512, 0, stream>>>(KHAT, SRC, ZP, u_init, Wf1, bfv, Wf2, UBUF);
  k_out<<<dim3(Nn/256, Bn), 256, 0, stream>>>(WPROJ, UBUF, out);
}

// Round 2
// 869.858 us; speedup vs baseline: 1.1171x; 1.1171x over previous
//
#include <hip/hip_runtime.h>

#define Bn 16
#define Nn 1024
#define DIN 32
#define DZ 64
#define Fc 3
#define Pp 19
#define PPAD 20
#define Ee 171
#define ITERS 50
#define INV_SCALE (19.0f/1024.0f)
#define CHUNK 64
#define PF 4

// workspace offsets (in floats)
#define OFF_WPROJ 0         // [B][F][N][PPAD]  983040
#define OFF_FFULL 983040    // [B][N][F]        49152
#define OFF_FLAT  1033216   // [B][F][19]       912
#define OFF_UBUF  1034128   // [B][57]          912
#define OFF_BVALS 1035040   // [B][N][F]        49152   -- zero region start
#define OFF_ZACC  1084192   // [B][64]          1024
#define OFF_KHAT  1085216   // [B][F][16][19]   14592
#define OFF_SRC   1099808   // [B][F][16]       768
#define ZERO_FLOATS 65536   // BVALS+ZACC+KHAT+SRC contiguous

// ---------------- scatter boundary_vals (parallel, deterministic last-wins) ----------------
__global__ __launch_bounds__(1024) void k_scatter(const int* __restrict__ nodes,
                                                  const float* __restrict__ bvals,
                                                  float* __restrict__ bfull) {
  __shared__ int sn[1024];
  int tid = threadIdx.x;
  sn[tid] = nodes[tid];
  __syncthreads();
  int b = tid >> 6, j = tid & 63;
  int node = sn[tid];
  bool win = true;
  for (int j2 = j + 1; j2 < 64; j2++)
    if (sn[(b << 6) | j2] == node) { win = false; break; }
  if (win) {
    #pragma unroll
    for (int f = 0; f < Fc; f++)
      bfull[((size_t)b*Nn + node)*Fc + f] = bvals[(size_t)tid*Fc + f];
  }
}

// ---------------- encoder + POU softmax + f_full + zacc partials ----------------
__global__ __launch_bounds__(128) void k_encode(
    const float* __restrict__ x, const float* __restrict__ Wenc, const float* __restrict__ benc,
    const float* __restrict__ Wsrc, const float* __restrict__ bsrc, const float* __restrict__ Wpou,
    const float* __restrict__ bfull, float* __restrict__ wproj, float* __restrict__ ffull,
    float* __restrict__ zacc) {
  __shared__ float sWenc[DIN*DZ];
  __shared__ float sWpou[DZ*57];
  __shared__ float sWsrc[DZ*Fc];
  int tid = threadIdx.x;
  for (int t = tid; t < DIN*DZ; t += 128) sWenc[t] = Wenc[t];
  for (int t = tid; t < DZ*57; t += 128) sWpou[t] = Wpou[t];
  for (int t = tid; t < DZ*Fc; t += 128) sWsrc[t] = Wsrc[t];
  __syncthreads();
  int g = blockIdx.x*128 + tid;         // b*N + i
  int b = g >> 10, i = g & 1023;
  float xr[DIN];
  const float* xp = x + (size_t)g*DIN;
  #pragma unroll
  for (int k = 0; k < DIN; k += 4) {
    float4 t4 = *(const float4*)(xp + k);
    xr[k] = t4.x; xr[k+1] = t4.y; xr[k+2] = t4.z; xr[k+3] = t4.w;
  }
  float l[57];
  #pragma unroll
  for (int o = 0; o < 57; o++) l[o] = 0.f;
  float ff[3] = {bsrc[0], bsrc[1], bsrc[2]};
  int lane = tid & 63;
  for (int d = 0; d < DZ; d++) {
    float zd = benc[d];
    #pragma unroll
    for (int k = 0; k < DIN; k++) zd = fmaf(xr[k], sWenc[k*DZ + d], zd);
    zd = tanhf(zd);
    #pragma unroll
    for (int o = 0; o < 57; o++) l[o] = fmaf(zd, sWpou[d*57 + o], l[o]);
    #pragma unroll
    for (int f = 0; f < Fc; f++) ff[f] = fmaf(zd, sWsrc[d*Fc + f], ff[f]);
    float zs = zd;
    #pragma unroll
    for (int off = 32; off > 0; off >>= 1) zs += __shfl_xor(zs, off, 64);
    if (lane == 0) atomicAdd(&zacc[b*DZ + d], zs);
  }
  #pragma unroll
  for (int f = 0; f < Fc; f++) ffull[(size_t)g*Fc + f] = ff[f];
  #pragma unroll
  for (int f = 0; f < Fc; f++) {
    float bv = bfull[(size_t)g*Fc + f];
    l[16*3+f] += bv; l[17*3+f] += bv; l[18*3+f] += bv;
  }
  #pragma unroll
  for (int f = 0; f < Fc; f++) {
    float m = l[f];
    #pragma unroll
    for (int p = 1; p < Pp; p++) m = fmaxf(m, l[p*3+f]);
    float ex[Pp]; float s = 0.f;
    #pragma unroll
    for (int p = 0; p < Pp; p++) { ex[p] = __expf(l[p*3+f] - m); s += ex[p]; }
    float inv = 1.f / s;
    float* wp = wproj + ((size_t)(b*Fc + f)*Nn + i)*PPAD;
    #pragma unroll
    for (int p = 0; p < Pp; p++) wp[p] = ex[p]*inv;
  }
}

// ---------------- f_latent[b,f,q] = (1/scale) sum_i W[q,i] f_full[i,f] ----------------
__global__ __launch_bounds__(256) void k_flat(const float* __restrict__ wproj,
                                              const float* __restrict__ ffull,
                                              float* __restrict__ flat) {
  int bf = blockIdx.x;                 // b*3+f
  int b = bf / 3, f = bf % 3;
  float acc[Pp];
  #pragma unroll
  for (int q = 0; q < Pp; q++) acc[q] = 0.f;
  for (int i = threadIdx.x; i < Nn; i += 256) {
    float fv = ffull[((size_t)b*Nn + i)*Fc + f];
    const float* row = wproj + ((size_t)bf*Nn + i)*PPAD;
    #pragma unroll
    for (int q = 0; q < Pp; q++) acc[q] = fmaf(row[q], fv, acc[q]);
  }
  #pragma unroll
  for (int q = 0; q < Pp; q++) {
    float v = acc[q];
    #pragma unroll
    for (int off = 32; off > 0; off >>= 1) v += __shfl_xor(v, off, 64);
    acc[q] = v;
  }
  __shared__ float red[4][Pp];
  int wave = threadIdx.x >> 6, lane = threadIdx.x & 63;
  if (lane == 0) {
    #pragma unroll
    for (int q = 0; q < Pp; q++) red[wave][q] = acc[q];
  }
  __syncthreads();
  if (threadIdx.x < Pp) {
    float s = red[0][threadIdx.x] + red[1][threadIdx.x] + red[2][threadIdx.x] + red[3][threadIdx.x];
    flat[bf*Pp + threadIdx.x] = s * INV_SCALE;
  }
}

// ---------------- the heavy pass: stream K & M once, deep prefetch ----------------
__global__ __launch_bounds__(256, 3) void k_project(
    const float* __restrict__ Kl, const float* __restrict__ Ml,
    const float* __restrict__ wproj, const float* __restrict__ flat,
    float* __restrict__ khat, float* __restrict__ srca) {
  int chunk = blockIdx.x;              // 16 i-chunks of 64
  int bf = blockIdx.y;                 // 48
  int i0 = chunk * CHUNK;
  const float* Kb = Kl + (size_t)bf*Nn*Nn;
  const float* Mb = Ml + (size_t)bf*Nn*Nn;
  const float* Wp = wproj + (size_t)bf*Nn*PPAD;
  const float* Wrow0 = Wp + (size_t)i0*PPAD;      // block-uniform -> scalar loads
  int tid = threadIdx.x;
  float fl[Pp];
  #pragma unroll
  for (int q = 0; q < Pp; q++) fl[q] = flat[bf*Pp + q];
  int j0 = tid * 4;
  float v[4];
  #pragma unroll
  for (int r = 0; r < 4; r++) {
    const float* row = Wp + (size_t)(j0 + r)*PPAD;
    float s = 0.f;
    #pragma unroll
    for (int q = 0; q < Pp; q++) s = fmaf(row[q], fl[q], s);
    v[r] = s;
  }
  float acc[16][4];
  float sa[16];
  #pragma unroll
  for (int p = 0; p < 16; p++) { acc[p][0]=0.f; acc[p][1]=0.f; acc[p][2]=0.f; acc[p][3]=0.f; sa[p]=0.f; }
  const float* kp = Kb + (size_t)i0*Nn + j0;
  const float* mp = Mb + (size_t)i0*Nn + j0;
  float4 kbuf[PF], mbuf[PF];
  #pragma unroll
  for (int s = 0; s < PF; s++) {
    kbuf[s] = *(const float4*)(kp + (size_t)s*Nn);
    mbuf[s] = *(const float4*)(mp + (size_t)s*Nn);
  }
  for (int ii = 0; ii < CHUNK; ii += PF) {
    #pragma unroll
    for (int s = 0; s < PF; s++) {
      float4 k4 = kbuf[s], m4 = mbuf[s];
      int nxt = (ii + PF + s) & (CHUNK - 1);   // wraps to rows 0..3 at the tail (cached, harmless)
      kbuf[s] = *(const float4*)(kp + (size_t)nxt*Nn);
      mbuf[s] = *(const float4*)(mp + (size_t)nxt*Nn);
      const float* w = Wrow0 + (size_t)(ii + s)*PPAD;
      float tm = m4.x*v[0] + m4.y*v[1] + m4.z*v[2] + m4.w*v[3];
      #pragma unroll
      for (int p = 0; p < 16; p++) {
        float wv = w[p];
        acc[p][0] = fmaf(wv, k4.x, acc[p][0]);
        acc[p][1] = fmaf(wv, k4.y, acc[p][1]);
        acc[p][2] = fmaf(wv, k4.z, acc[p][2]);
        acc[p][3] = fmaf(wv, k4.w, acc[p][3]);
        sa[p] = fmaf(wv, tm, sa[p]);
      }
    }
  }
  // stage 2: contract partial T against W^T over this thread's 4 columns
  float wrow[4][Pp];
  #pragma unroll
  for (int r = 0; r < 4; r++) {
    const float* row = Wp + (size_t)(j0 + r)*PPAD;
    #pragma unroll
    for (int q = 0; q < Pp; q++) wrow[r][q] = row[q];
  }
  int lane = tid & 63;
  #pragma unroll
  for (int p = 0; p < 16; p++) {
    float pr[Pp];
    #pragma unroll
    for (int q = 0; q < Pp; q++)
      pr[q] = acc[p][0]*wrow[0][q] + acc[p][1]*wrow[1][q] + acc[p][2]*wrow[2][q] + acc[p][3]*wrow[3][q];
    #pragma unroll
    for (int q = 0; q < Pp; q++) {
      float vq = pr[q];
      #pragma unroll
      for (int off = 32; off > 0; off >>= 1) vq += __shfl_xor(vq, off, 64);
      pr[q] = vq;
    }
    if (lane == 0) {
      for (int q = 0; q < Pp; q++)
        atomicAdd(&khat[(bf*16 + p)*Pp + q], pr[q] * INV_SCALE);
    }
  }
  #pragma unroll
  for (int p = 0; p < 16; p++) {
    float vq = sa[p];
    #pragma unroll
    for (int off = 32; off > 0; off >>= 1) vq += __shfl_xor(vq, off, 64);
    sa[p] = vq;
  }
  if (lane == 0) {
    for (int p = 0; p < 16; p++) atomicAdd(&srca[bf*16 + p], sa[p] * INV_SCALE);
  }
}

// ---------------- damped fixed-point solver: one block per batch ----------------
#define ABS 65   // padded stride for sA/sB (kills 16-way bank conflict)
__global__ __launch_bounds__(704, 1) void k_solve(
    const float* __restrict__ khat, const float* __restrict__ srca,
    const float* __restrict__ zacc, const float* __restrict__ Wz,
    const float* __restrict__ u_init, const float* __restrict__ Wf1,
    const float* __restrict__ bfv, const float* __restrict__ Wf2,
    float* __restrict__ ubuf) {
  int b = blockIdx.x;
  __shared__ float u_s[57];
  __shared__ float flux_s[Ee*Fc];
  __shared__ float sW1[6*DZ];
  __shared__ float sW2[DZ*Fc];
  __shared__ float sbz[DZ];
  __shared__ float sK[Fc*16*Pp];
  __shared__ float ssrc[Fc*16];
  __shared__ float sA[Pp*ABS];
  __shared__ float sB[Pp*ABS];
  int tid = threadIdx.x;
  for (int t = tid; t < 6*DZ; t += 704) sW1[t] = Wf1[t];
  for (int t = tid; t < DZ*Fc; t += 704) sW2[t] = Wf2[t];
  if (tid < DZ) {
    float s = 0.f;
    for (int k = 0; k < DZ; k++) s = fmaf(zacc[b*DZ + k], Wz[k*DZ + tid], s);
    sbz[tid] = bfv[tid] + s * (1.f/1024.f);
  }
  for (int t = tid; t < Fc*16*Pp; t += 704) sK[t] = khat[b*Fc*16*Pp + t];
  if (tid < 48) ssrc[tid] = srca[b*48 + tid];
  if (tid < 57) u_s[tid] = u_init[b*57 + tid];
  __syncthreads();
  int e = tid >> 2, h = tid & 3;
  bool active = (tid < 4*Ee);
  int ei = 0, ej = 0;
  if (active) {
    int r = e, i = 0;
    while (r >= 18 - i) { r -= 18 - i; i++; }
    ei = i; ej = i + 1 + r;
  }
  int d0 = h * 16;
  for (int it = 0; it < ITERS; it++) {
    // phase 0: A[p,d] = sum_f u[p,f] W1[f,d];  B[p,d] = sum_f u[p,f] W1[3+f,d]
    for (int t = tid; t < 2*Pp*DZ; t += 704) {
      int half = (t >= Pp*DZ);
      int t2 = half ? t - Pp*DZ : t;
      int p = t2 >> 6, d = t2 & 63;
      const float* w1 = sW1 + (half ? 3*DZ : 0) + d;
      float s = u_s[p*3+0]*w1[0] + u_s[p*3+1]*w1[DZ] + u_s[p*3+2]*w1[2*DZ];
      (half ? sB : sA)[p*ABS + d] = s;
    }
    __syncthreads();
    if (active) {
      const float* Ap = sA + ei*ABS;
      const float* Bp = sB + ej*ABS;
      float fl0 = 0.f, fl1 = 0.f, fl2 = 0.f;
      for (int dd = 0; dd < 16; dd++) {
        int d = d0 + dd;
        float pre = sbz[d] + Ap[d] + Bp[d];
        float xc = fminf(fmaxf(pre, -20.f), 20.f);
        float t = __expf(2.f * xc);
        float th = (t - 1.f) / (t + 1.f);
        fl0 = fmaf(th, sW2[d*3 + 0], fl0);
        fl1 = fmaf(th, sW2[d*3 + 1], fl1);
        fl2 = fmaf(th, sW2[d*3 + 2], fl2);
      }
      fl0 += __shfl_xor(fl0, 1, 64); fl0 += __shfl_xor(fl0, 2, 64);
      fl1 += __shfl_xor(fl1, 1, 64); fl1 += __shfl_xor(fl1, 2, 64);
      fl2 += __shfl_xor(fl2, 1, 64); fl2 += __shfl_xor(fl2, 2, 64);
      if (h == 0) { flux_s[e*3+0] = fl0; flux_s[e*3+1] = fl1; flux_s[e*3+2] = fl2; }
    }
    __syncthreads();
    if (tid < 57) {
      int p = tid / 3, f = tid % 3;
      float u_old = u_s[tid];
      float r_;
      if (p < 16) {
        float diff = 0.f;
        for (int q = 0; q < Pp; q++) diff = fmaf(sK[(f*16 + p)*Pp + q], u_s[q*3 + f], diff);
        float ft = 0.f;
        for (int o = 0; o < Pp; o++) {
          if (o == p) continue;
          int i_ = (o < p) ? o : p;
          int j_ = (o < p) ? p : o;
          int eidx = i_*Pp - (i_*(i_+1))/2 + (j_ - i_ - 1);
          float sgn = (o < p) ? 1.f : -1.f;
          ft += sgn * flux_s[eidx*3 + f];
        }
        r_ = diff - ssrc[f*16 + p] - ft;
      } else {
        r_ = u_old - ((p == 16) ? 1.f : 0.f);
      }
      u_s[tid] = u_old - 0.1f * r_;
    }
    __syncthreads();
  }
  if (tid < 57) ubuf[b*57 + tid] = u_s[tid];
}

// ---------------- u_fine = einsum('bpif,bpf->bif') ----------------
__global__ __launch_bounds__(256) void k_out(const float* __restrict__ wproj,
                                             const float* __restrict__ ubuf,
                                             float* __restrict__ out) {
  __shared__ float u_s[57];
  int b = blockIdx.y;
  int i = blockIdx.x*256 + threadIdx.x;
  if (threadIdx.x < 57) u_s[threadIdx.x] = ubuf[b*57 + threadIdx.x];
  __syncthreads();
  #pragma unroll
  for (int f = 0; f < Fc; f++) {
    const float* row = wproj + ((size_t)(b*Fc + f)*Nn + i)*PPAD;
    float s = 0.f;
    #pragma unroll
    for (int p = 0; p < Pp; p++) s = fmaf(row[p], u_s[p*3 + f], s);
    out[((size_t)b*Nn + i)*Fc + f] = s;
  }
}

extern "C" void kernel_launch(void* const* d_in, const int* in_sizes, int n_in,
                              void* d_out, int out_size, void* d_ws, size_t ws_size,
                              hipStream_t stream) {
  const float* in_tokens = (const float*)d_in[0];
  const float* K_list    = (const float*)d_in[1];
  const float* M_list    = (const float*)d_in[2];
  const int*   dnodes    = (const int*)d_in[3];
  const float* bvals     = (const float*)d_in[4];
  const float* u_init    = (const float*)d_in[5];
  const float* W_enc     = (const float*)d_in[6];
  const float* b_enc     = (const float*)d_in[7];
  const float* W_src     = (const float*)d_in[8];
  const float* b_src     = (const float*)d_in[9];
  const float* W_pou     = (const float*)d_in[10];
  const float* Wf1       = (const float*)d_in[11];
  const float* Wz        = (const float*)d_in[12];
  const float* bfv       = (const float*)d_in[13];
  const float* Wf2       = (const float*)d_in[14];
  float* ws  = (float*)d_ws;
  float* out = (float*)d_out;

  float* WPROJ = ws + OFF_WPROJ;
  float* FFULL = ws + OFF_FFULL;
  float* FLAT  = ws + OFF_FLAT;
  float* UBUF  = ws + OFF_UBUF;
  float* BVALS = ws + OFF_BVALS;
  float* ZACC  = ws + OFF_ZACC;
  float* KHAT  = ws + OFF_KHAT;
  float* SRC   = ws + OFF_SRC;

  hipMemsetAsync(ws + OFF_BVALS, 0, (size_t)ZERO_FLOATS * sizeof(float), stream);
  k_scatter<<<1, 1024, 0, stream>>>(dnodes, bvals, BVALS);
  k_encode<<<128, 128, 0, stream>>>(in_tokens, W_enc, b_enc, W_src, b_src, W_pou,
                                    BVALS, WPROJ, FFULL, ZACC);
  k_flat<<<Bn*Fc, 256, 0, stream>>>(WPROJ, FFULL, FLAT);
  k_project<<<dim3(Nn/CHUNK, Bn*Fc), 256, 0, stream>>>(K_list, M_list, WPROJ, FLAT, KHAT, SRC);
  k_solve<<<Bn, 704, 0, stream>>>(KHAT, SRC, ZACC, Wz, u_init, Wf1, bfv, Wf2, UBUF);
  k_out<<<dim3(Nn/256, Bn), 256, 0, stream>>>(WPROJ, UBUF, out);
}